// Round 2
// baseline (636.843 us; speedup 1.0000x reference)
//
#include <hip/hip_runtime.h>
#include <math.h>

#define EPS 1e-8f

__device__ __forceinline__ float wave_reduce_sum(float v) {
#pragma unroll
  for (int off = 32; off > 0; off >>= 1)
    v += __shfl_xor(v, off, 64);
  return v;
}

__device__ __forceinline__ float wave_reduce_max(float v) {
#pragma unroll
  for (int off = 32; off > 0; off >>= 1)
    v = fmaxf(v, __shfl_xor(v, off, 64));
  return v;
}

// ---------- edge sort by dst (counting sort, 1 bin per node) ----------
__global__ __launch_bounds__(256) void hist_kernel(const int* __restrict__ dst,
                                                   int* __restrict__ hist,
                                                   int E) {
  int e = blockIdx.x * blockDim.x + threadIdx.x;
  if (e < E) atomicAdd(&hist[dst[e]], 1);
}

// Single-block exclusive scan over nb bins (nb ~ 50k). Each thread owns a
// contiguous chunk; hist re-read in pass 2 instead of caching (reg pressure).
__global__ __launch_bounds__(1024) void scan_kernel(const int* __restrict__ hist,
                                                    int* __restrict__ base,
                                                    int nb) {
  __shared__ int tsum[1024];
  int t = threadIdx.x;
  int per = (nb + 1023) / 1024;
  int lo = t * per;
  int s = 0;
  for (int i = 0; i < per; ++i) {
    int idx = lo + i;
    if (idx < nb) s += hist[idx];
  }
  tsum[t] = s;
  __syncthreads();
  for (int off = 1; off < 1024; off <<= 1) {
    int v = 0;
    if (t >= off) v = tsum[t - off];
    __syncthreads();
    if (t >= off) tsum[t] += v;
    __syncthreads();
  }
  int run = (t == 0) ? 0 : tsum[t - 1];
  for (int i = 0; i < per; ++i) {
    int idx = lo + i;
    if (idx < nb) {
      base[idx] = run;
      run += hist[idx];
    }
  }
}

// base[] is consumed as a cursor array (atomic bump); within-dst order is
// nondeterministic, which is fine: gate is per-edge, aggregation is atomic.
__global__ __launch_bounds__(256) void scatter_kernel(
    const int* __restrict__ src, const int* __restrict__ dst,
    int* __restrict__ cursor, int* __restrict__ ssrc, int* __restrict__ sdst,
    int E) {
  int e = blockIdx.x * blockDim.x + threadIdx.x;
  if (e < E) {
    int d = dst[e];
    int pos = atomicAdd(&cursor[d], 1);
    ssrc[pos] = src[e];
    sdst[pos] = d;
  }
}

// ---------- node phase ----------
// One wave per node: L2 norm + self-loop init of agg.
template <int D>
__global__ __launch_bounds__(256) void node_norm_init(
    const float* __restrict__ x, float* __restrict__ norms,
    float* __restrict__ agg, int N) {
  constexpr int V = D / 64;
  int node = (int)((blockIdx.x * blockDim.x + threadIdx.x) >> 6);
  int lane = threadIdx.x & 63;
  if (node >= N) return;
  const float* row = x + (size_t)node * D + lane * V;
  float v[V];
  if constexpr (V == 2) {
    float2 t = *(const float2*)row;
    v[0] = t.x; v[1] = t.y;
  } else {
    float4 t = *(const float4*)row;
    v[0] = t.x; v[1] = t.y; v[2] = t.z; v[3] = t.w;
  }
  float ss = 0.f;
#pragma unroll
  for (int q = 0; q < V; ++q) ss += v[q] * v[q];
  ss = wave_reduce_sum(ss);
  if (lane == 0) norms[node] = sqrtf(ss);
  bool pass = ss > 0.5f * fmaxf(ss, EPS);
  float* arow = agg + (size_t)node * D + lane * V;
#pragma unroll
  for (int q = 0; q < V; ++q) arow[q] = pass ? v[q] : 0.f;
}

// ---------- edge phase ----------
// One wave per (dst-sorted) edge: cosine gate + rare atomic scatter-add.
template <int D>
__global__ __launch_bounds__(256) void edge_conv(
    const float* __restrict__ feat, const float* __restrict__ norms,
    const int* __restrict__ src, const int* __restrict__ dst,
    float* __restrict__ agg, int E) {
  constexpr int V = D / 64;
  int e = (int)((blockIdx.x * blockDim.x + threadIdx.x) >> 6);
  int lane = threadIdx.x & 63;
  if (e >= E) return;
  int s = src[e];
  int d = dst[e];
  const float* srow = feat + (size_t)s * D + lane * V;
  const float* drow = feat + (size_t)d * D + lane * V;
  float sv[V], dv[V];
  if constexpr (V == 2) {
    float2 a = *(const float2*)srow;
    float2 b = *(const float2*)drow;
    sv[0] = a.x; sv[1] = a.y;
    dv[0] = b.x; dv[1] = b.y;
  } else {
    float4 a = *(const float4*)srow;
    float4 b = *(const float4*)drow;
    sv[0] = a.x; sv[1] = a.y; sv[2] = a.z; sv[3] = a.w;
    dv[0] = b.x; dv[1] = b.y; dv[2] = b.z; dv[3] = b.w;
  }
  float dot = 0.f;
#pragma unroll
  for (int q = 0; q < V; ++q) dot += sv[q] * dv[q];
  dot = wave_reduce_sum(dot);  // wave-uniform gate
  float denom = fmaxf(norms[s] * norms[d], EPS);
  if (dot > 0.5f * denom) {
    float* arow = agg + (size_t)d * D + lane * V;
#pragma unroll
    for (int q = 0; q < V; ++q) atomicAdd(&arow[q], sv[q]);
  }
}

// ---------- GEMM: C[M,N] = act(A @ W^T + b), 64x64 tile, 4x4/thread ----------
template <int BK, bool RELU>
__global__ __launch_bounds__(256) void gemm_bias(
    const float* __restrict__ A, const float* __restrict__ W,
    const float* __restrict__ bias, float* __restrict__ C,
    int M, int N, int K) {
  __shared__ float As[BK][68];
  __shared__ float Bs[BK][68];
  const int tid = threadIdx.x;
  const int m0 = blockIdx.x * 64;
  const int n0 = blockIdx.y * 64;
  const int mv = tid >> 3;
  const int kv = (tid & 7) * 4;
  float acc[4][4] = {};
  for (int k0 = 0; k0 < K; k0 += BK) {
#pragma unroll
    for (int i = 0; i < 2; ++i) {
      int r = mv + i * 32;
      int gm = m0 + r;
      float4 a = (gm < M) ? *(const float4*)&A[(size_t)gm * K + k0 + kv]
                          : make_float4(0.f, 0.f, 0.f, 0.f);
      As[kv + 0][r] = a.x; As[kv + 1][r] = a.y;
      As[kv + 2][r] = a.z; As[kv + 3][r] = a.w;
      float4 b = *(const float4*)&W[(size_t)(n0 + r) * K + k0 + kv];
      Bs[kv + 0][r] = b.x; Bs[kv + 1][r] = b.y;
      Bs[kv + 2][r] = b.z; Bs[kv + 3][r] = b.w;
    }
    __syncthreads();
    const int ms = (tid & 15) * 4;
    const int ns = (tid >> 4) * 4;
#pragma unroll
    for (int kk = 0; kk < BK; ++kk) {
      float4 a4 = *(const float4*)&As[kk][ms];
      float4 b4 = *(const float4*)&Bs[kk][ns];
      float av[4] = {a4.x, a4.y, a4.z, a4.w};
      float bv[4] = {b4.x, b4.y, b4.z, b4.w};
#pragma unroll
      for (int i = 0; i < 4; ++i)
#pragma unroll
        for (int j = 0; j < 4; ++j) acc[i][j] += av[i] * bv[j];
    }
    __syncthreads();
  }
  const int ms = (tid & 15) * 4;
  const int ns = (tid >> 4) * 4;
  float4 bb = *(const float4*)&bias[n0 + ns];
  float bv[4] = {bb.x, bb.y, bb.z, bb.w};
#pragma unroll
  for (int i = 0; i < 4; ++i) {
    int gm = m0 + ms + i;
    if (gm < M) {
      float t0 = acc[i][0] + bv[0];
      float t1 = acc[i][1] + bv[1];
      float t2 = acc[i][2] + bv[2];
      float t3 = acc[i][3] + bv[3];
      if (RELU) {
        t0 = fmaxf(t0, 0.f); t1 = fmaxf(t1, 0.f);
        t2 = fmaxf(t2, 0.f); t3 = fmaxf(t3, 0.f);
      }
      float4 o = {t0, t1, t2, t3};
      *(float4*)&C[(size_t)gm * N + n0 + ns] = o;
    }
  }
}

__global__ __launch_bounds__(256) void log_softmax64(float* __restrict__ out,
                                                     int N) {
  int row = (int)((blockIdx.x * blockDim.x + threadIdx.x) >> 6);
  int lane = threadIdx.x & 63;
  if (row >= N) return;
  float v = out[(size_t)row * 64 + lane];
  float mx = wave_reduce_max(v);
  float e = expf(v - mx);
  float s = wave_reduce_sum(e);
  out[(size_t)row * 64 + lane] = v - mx - logf(s);
}

extern "C" void kernel_launch(void* const* d_in, const int* in_sizes, int n_in,
                              void* d_out, int out_size, void* d_ws,
                              size_t ws_size, hipStream_t stream) {
  const float* x  = (const float*)d_in[0];
  const int* eidx = (const int*)d_in[1];
  const float* W1 = (const float*)d_in[2];
  const float* b1 = (const float*)d_in[3];
  const float* W2 = (const float*)d_in[4];
  const float* b2 = (const float*)d_in[5];
  float* out = (float*)d_out;

  const int N = in_sizes[0] / 128;  // 50000
  const int E = in_sizes[1] / 2;    // 800000
  const int* src = eidx;
  const int* dst = eidx + E;

  // ws layout (floats): h[N*256] | agg[N*256] | norms[N] | normh[N] |
  //                     hist[N] (int) | ssrc[E] (int) | sdst[E] (int)
  float* h     = (float*)d_ws;
  float* agg   = h + (size_t)N * 256;
  float* norms = agg + (size_t)N * 256;
  float* normh = norms + N;
  int* hist    = (int*)(normh + N);
  int* ssrc    = hist + N;
  int* sdst    = ssrc + E;

  // ---- sort edges by dst (shared by both layers) ----
  hipMemsetAsync(hist, 0, (size_t)N * sizeof(int), stream);
  hist_kernel<<<(E + 255) / 256, 256, 0, stream>>>(dst, hist, E);
  scan_kernel<<<1, 1024, 0, stream>>>(hist, hist, N);  // in-place: base=cursor
  scatter_kernel<<<(E + 255) / 256, 256, 0, stream>>>(src, dst, hist, ssrc,
                                                      sdst, E);

  // ---- layer 1 (D=128) ----
  node_norm_init<128><<<(N + 3) / 4, 256, 0, stream>>>(x, norms, agg, N);
  edge_conv<128><<<(E + 3) / 4, 256, 0, stream>>>(x, norms, ssrc, sdst, agg, E);
  gemm_bias<32, true><<<dim3((N + 63) / 64, 4), 256, 0, stream>>>(
      agg, W1, b1, h, N, 256, 128);

  // ---- layer 2 (D=256) ----
  node_norm_init<256><<<(N + 3) / 4, 256, 0, stream>>>(h, normh, agg, N);
  edge_conv<256><<<(E + 3) / 4, 256, 0, stream>>>(h, normh, ssrc, sdst, agg, E);
  gemm_bias<32, false><<<dim3((N + 63) / 64, 1), 256, 0, stream>>>(
      agg, W2, b2, out, N, 64, 256);

  log_softmax64<<<(N + 3) / 4, 256, 0, stream>>>(out, N);
}

// Round 3
// 474.286 us; speedup vs baseline: 1.3427x; 1.3427x over previous
//
#include <hip/hip_runtime.h>
#include <math.h>

#define EPS 1e-8f

__device__ __forceinline__ float wave_reduce_sum(float v) {
#pragma unroll
  for (int off = 32; off > 0; off >>= 1)
    v += __shfl_xor(v, off, 64);
  return v;
}

__device__ __forceinline__ float wave_reduce_max(float v) {
#pragma unroll
  for (int off = 32; off > 0; off >>= 1)
    v = fmaxf(v, __shfl_xor(v, off, 64));
  return v;
}

// ---------------- counting sort by dst -> CSR ----------------
__global__ __launch_bounds__(256) void hist_kernel(const int* __restrict__ dst,
                                                   int* __restrict__ hist,
                                                   int E) {
  int e = blockIdx.x * blockDim.x + threadIdx.x;
  if (e < E) atomicAdd(&hist[dst[e]], 1);
}

// Block-local exclusive scan: each block handles 1024 bins (4/thread).
// hist[] becomes block-local exclusive prefixes; bsum[blk] = block total.
__global__ __launch_bounds__(256) void scan_local(int* __restrict__ hist,
                                                  int* __restrict__ bsum,
                                                  int nb) {
  __shared__ int tsum[256];
  int t = threadIdx.x;
  int base = blockIdx.x * 1024 + t * 4;
  int v0 = 0, v1 = 0, v2 = 0, v3 = 0;
  if (base + 3 < nb) {
    int4 q = *(const int4*)&hist[base];
    v0 = q.x; v1 = q.y; v2 = q.z; v3 = q.w;
  } else {
    if (base + 0 < nb) v0 = hist[base + 0];
    if (base + 1 < nb) v1 = hist[base + 1];
    if (base + 2 < nb) v2 = hist[base + 2];
  }
  tsum[t] = v0 + v1 + v2 + v3;
  __syncthreads();
  for (int off = 1; off < 256; off <<= 1) {
    int u = 0;
    if (t >= off) u = tsum[t - off];
    __syncthreads();
    if (t >= off) tsum[t] += u;
    __syncthreads();
  }
  int excl = (t == 0) ? 0 : tsum[t - 1];
  int e0 = excl, e1 = excl + v0, e2 = e1 + v1, e3 = e2 + v2;
  if (base + 3 < nb) {
    *(int4*)&hist[base] = make_int4(e0, e1, e2, e3);
  } else {
    if (base + 0 < nb) hist[base + 0] = e0;
    if (base + 1 < nb) hist[base + 1] = e1;
    if (base + 2 < nb) hist[base + 2] = e2;
  }
  if (t == 255) bsum[blockIdx.x] = tsum[255];
}

// Single block: exclusive scan of block sums (nblk <= 256).
__global__ __launch_bounds__(256) void scan_bsum(int* __restrict__ bsum,
                                                 int nblk) {
  __shared__ int sh[256];
  int t = threadIdx.x;
  sh[t] = (t < nblk) ? bsum[t] : 0;
  __syncthreads();
  for (int off = 1; off < 256; off <<= 1) {
    int u = 0;
    if (t >= off) u = sh[t - off];
    __syncthreads();
    if (t >= off) sh[t] += u;
    __syncthreads();
  }
  if (t < nblk) bsum[t] = (t == 0) ? 0 : sh[t - 1];
}

__global__ __launch_bounds__(256) void add_bsum(int* __restrict__ hist,
                                                const int* __restrict__ bsum,
                                                int nb) {
  int i = blockIdx.x * blockDim.x + threadIdx.x;
  if (i < nb) hist[i] += bsum[i >> 10];
}

// cursor = global exclusive base per dst; after this kernel cursor[d] = end(d).
__global__ __launch_bounds__(256) void scatter_kernel(
    const int* __restrict__ src, const int* __restrict__ dst,
    int* __restrict__ cursor, int* __restrict__ ssrc, int E) {
  int e = blockIdx.x * blockDim.x + threadIdx.x;
  if (e < E) {
    int pos = atomicAdd(&cursor[dst[e]], 1);
    ssrc[pos] = src[e];
  }
}

// ---------------- node norms ----------------
template <int D>
__global__ __launch_bounds__(256) void node_norm(const float* __restrict__ x,
                                                 float* __restrict__ norms,
                                                 int N) {
  constexpr int V = D / 64;
  int node = (int)((blockIdx.x * blockDim.x + threadIdx.x) >> 6);
  int lane = threadIdx.x & 63;
  if (node >= N) return;
  const float* row = x + (size_t)node * D + lane * V;
  float ss = 0.f;
  if constexpr (V == 2) {
    float2 t = *(const float2*)row;
    ss = t.x * t.x + t.y * t.y;
  } else {
    float4 t = *(const float4*)row;
    ss = t.x * t.x + t.y * t.y + t.z * t.z + t.w * t.w;
  }
  ss = wave_reduce_sum(ss);
  if (lane == 0) norms[node] = sqrtf(ss);
}

// ---------------- CSR conv: one wave per dst node ----------------
// Register accumulator, self-loop folded in, no atomics, agg written once.
template <int D>
__global__ __launch_bounds__(256) void csr_conv(
    const float* __restrict__ feat, const float* __restrict__ norms,
    const int* __restrict__ ssrc, const int* __restrict__ endoff,
    float* __restrict__ agg, int N) {
  constexpr int V = D / 64;
  int node = (int)((blockIdx.x * blockDim.x + threadIdx.x) >> 6);
  int lane = threadIdx.x & 63;
  if (node >= N) return;
  int start = (node == 0) ? 0 : endoff[node - 1];
  int end = endoff[node];
  const float* drow = feat + (size_t)node * D + lane * V;
  float dv[V];
  if constexpr (V == 2) {
    float2 t = *(const float2*)drow;
    dv[0] = t.x; dv[1] = t.y;
  } else {
    float4 t = *(const float4*)drow;
    dv[0] = t.x; dv[1] = t.y; dv[2] = t.z; dv[3] = t.w;
  }
  float ssq = 0.f;
#pragma unroll
  for (int q = 0; q < V; ++q) ssq += dv[q] * dv[q];
  ssq = wave_reduce_sum(ssq);
  float nd = sqrtf(ssq);
  float acc[V];
  bool selfpass = ssq > 0.5f * fmaxf(ssq, EPS);
#pragma unroll
  for (int q = 0; q < V; ++q) acc[q] = selfpass ? dv[q] : 0.f;

  int i = start;
  for (; i + 2 <= end; i += 2) {
    int s0 = ssrc[i];
    int s1 = ssrc[i + 1];
    const float* r0 = feat + (size_t)s0 * D + lane * V;
    const float* r1 = feat + (size_t)s1 * D + lane * V;
    float sv0[V], sv1[V];
    if constexpr (V == 2) {
      float2 a = *(const float2*)r0;
      float2 b = *(const float2*)r1;
      sv0[0] = a.x; sv0[1] = a.y;
      sv1[0] = b.x; sv1[1] = b.y;
    } else {
      float4 a = *(const float4*)r0;
      float4 b = *(const float4*)r1;
      sv0[0] = a.x; sv0[1] = a.y; sv0[2] = a.z; sv0[3] = a.w;
      sv1[0] = b.x; sv1[1] = b.y; sv1[2] = b.z; sv1[3] = b.w;
    }
    float ns0 = norms[s0];
    float ns1 = norms[s1];
    float d0 = 0.f, d1 = 0.f;
#pragma unroll
    for (int q = 0; q < V; ++q) { d0 += sv0[q] * dv[q]; d1 += sv1[q] * dv[q]; }
    d0 = wave_reduce_sum(d0);
    d1 = wave_reduce_sum(d1);
    if (d0 > 0.5f * fmaxf(ns0 * nd, EPS)) {
#pragma unroll
      for (int q = 0; q < V; ++q) acc[q] += sv0[q];
    }
    if (d1 > 0.5f * fmaxf(ns1 * nd, EPS)) {
#pragma unroll
      for (int q = 0; q < V; ++q) acc[q] += sv1[q];
    }
  }
  if (i < end) {
    int s0 = ssrc[i];
    const float* r0 = feat + (size_t)s0 * D + lane * V;
    float sv0[V];
    if constexpr (V == 2) {
      float2 a = *(const float2*)r0;
      sv0[0] = a.x; sv0[1] = a.y;
    } else {
      float4 a = *(const float4*)r0;
      sv0[0] = a.x; sv0[1] = a.y; sv0[2] = a.z; sv0[3] = a.w;
    }
    float ns0 = norms[s0];
    float d0 = 0.f;
#pragma unroll
    for (int q = 0; q < V; ++q) d0 += sv0[q] * dv[q];
    d0 = wave_reduce_sum(d0);
    if (d0 > 0.5f * fmaxf(ns0 * nd, EPS)) {
#pragma unroll
      for (int q = 0; q < V; ++q) acc[q] += sv0[q];
    }
  }

  float* arow = agg + (size_t)node * D + lane * V;
  if constexpr (V == 2) {
    *(float2*)arow = make_float2(acc[0], acc[1]);
  } else {
    *(float4*)arow = make_float4(acc[0], acc[1], acc[2], acc[3]);
  }
}

// ---------------- GEMM: C = act(A @ W^T + b), 64x64 tile ----------------
template <int BK, bool RELU>
__global__ __launch_bounds__(256) void gemm_bias(
    const float* __restrict__ A, const float* __restrict__ W,
    const float* __restrict__ bias, float* __restrict__ C,
    int M, int N, int K) {
  __shared__ float As[BK][68];
  __shared__ float Bs[BK][68];
  const int tid = threadIdx.x;
  const int m0 = blockIdx.x * 64;
  const int n0 = blockIdx.y * 64;
  const int mv = tid >> 3;
  const int kv = (tid & 7) * 4;
  float acc[4][4] = {};
  for (int k0 = 0; k0 < K; k0 += BK) {
#pragma unroll
    for (int i = 0; i < 2; ++i) {
      int r = mv + i * 32;
      int gm = m0 + r;
      float4 a = (gm < M) ? *(const float4*)&A[(size_t)gm * K + k0 + kv]
                          : make_float4(0.f, 0.f, 0.f, 0.f);
      As[kv + 0][r] = a.x; As[kv + 1][r] = a.y;
      As[kv + 2][r] = a.z; As[kv + 3][r] = a.w;
      float4 b = *(const float4*)&W[(size_t)(n0 + r) * K + k0 + kv];
      Bs[kv + 0][r] = b.x; Bs[kv + 1][r] = b.y;
      Bs[kv + 2][r] = b.z; Bs[kv + 3][r] = b.w;
    }
    __syncthreads();
    const int ms = (tid & 15) * 4;
    const int ns = (tid >> 4) * 4;
#pragma unroll
    for (int kk = 0; kk < BK; ++kk) {
      float4 a4 = *(const float4*)&As[kk][ms];
      float4 b4 = *(const float4*)&Bs[kk][ns];
      float av[4] = {a4.x, a4.y, a4.z, a4.w};
      float bv[4] = {b4.x, b4.y, b4.z, b4.w};
#pragma unroll
      for (int i = 0; i < 4; ++i)
#pragma unroll
        for (int j = 0; j < 4; ++j) acc[i][j] += av[i] * bv[j];
    }
    __syncthreads();
  }
  const int ms = (tid & 15) * 4;
  const int ns = (tid >> 4) * 4;
  float4 bb = *(const float4*)&bias[n0 + ns];
  float bv[4] = {bb.x, bb.y, bb.z, bb.w};
#pragma unroll
  for (int i = 0; i < 4; ++i) {
    int gm = m0 + ms + i;
    if (gm < M) {
      float t0 = acc[i][0] + bv[0];
      float t1 = acc[i][1] + bv[1];
      float t2 = acc[i][2] + bv[2];
      float t3 = acc[i][3] + bv[3];
      if (RELU) {
        t0 = fmaxf(t0, 0.f); t1 = fmaxf(t1, 0.f);
        t2 = fmaxf(t2, 0.f); t3 = fmaxf(t3, 0.f);
      }
      float4 o = {t0, t1, t2, t3};
      *(float4*)&C[(size_t)gm * N + n0 + ns] = o;
    }
  }
}

__global__ __launch_bounds__(256) void log_softmax64(float* __restrict__ out,
                                                     int N) {
  int row = (int)((blockIdx.x * blockDim.x + threadIdx.x) >> 6);
  int lane = threadIdx.x & 63;
  if (row >= N) return;
  float v = out[(size_t)row * 64 + lane];
  float mx = wave_reduce_max(v);
  float e = expf(v - mx);
  float s = wave_reduce_sum(e);
  out[(size_t)row * 64 + lane] = v - mx - logf(s);
}

extern "C" void kernel_launch(void* const* d_in, const int* in_sizes, int n_in,
                              void* d_out, int out_size, void* d_ws,
                              size_t ws_size, hipStream_t stream) {
  const float* x  = (const float*)d_in[0];
  const int* eidx = (const int*)d_in[1];
  const float* W1 = (const float*)d_in[2];
  const float* b1 = (const float*)d_in[3];
  const float* W2 = (const float*)d_in[4];
  const float* b2 = (const float*)d_in[5];
  float* out = (float*)d_out;

  const int N = in_sizes[0] / 128;  // 50000
  const int E = in_sizes[1] / 2;    // 800000
  const int* src = eidx;
  const int* dst = eidx + E;

  // ws (floats): h[N*256] | agg[N*256] | norms[N] | normh[N] |
  //              cursor[N](int) | ssrc[E](int) | bsum[256](int)
  float* h     = (float*)d_ws;
  float* agg   = h + (size_t)N * 256;
  float* norms = agg + (size_t)N * 256;
  float* normh = norms + N;
  int* cursor  = (int*)(normh + N);
  int* ssrc    = cursor + N;
  int* bsum    = ssrc + E;

  const int nblk = (N + 1023) / 1024;  // 49

  // ---- build CSR (by dst), shared by both layers ----
  hipMemsetAsync(cursor, 0, (size_t)N * sizeof(int), stream);
  hist_kernel<<<(E + 255) / 256, 256, 0, stream>>>(dst, cursor, E);
  scan_local<<<nblk, 256, 0, stream>>>(cursor, bsum, N);
  scan_bsum<<<1, 256, 0, stream>>>(bsum, nblk);
  add_bsum<<<(N + 255) / 256, 256, 0, stream>>>(cursor, bsum, N);
  scatter_kernel<<<(E + 255) / 256, 256, 0, stream>>>(src, dst, cursor, ssrc, E);
  // now cursor[d] == end offset of node d; start = cursor[d-1] (0 for d=0)

  // ---- layer 1 (D=128) ----
  node_norm<128><<<(N + 3) / 4, 256, 0, stream>>>(x, norms, N);
  csr_conv<128><<<(N + 3) / 4, 256, 0, stream>>>(x, norms, ssrc, cursor, agg, N);
  gemm_bias<32, true><<<dim3((N + 63) / 64, 4), 256, 0, stream>>>(
      agg, W1, b1, h, N, 256, 128);

  // ---- layer 2 (D=256) ----
  node_norm<256><<<(N + 3) / 4, 256, 0, stream>>>(h, normh, N);
  csr_conv<256><<<(N + 3) / 4, 256, 0, stream>>>(h, normh, ssrc, cursor, agg, N);
  gemm_bias<32, false><<<dim3((N + 63) / 64, 1), 256, 0, stream>>>(
      agg, W2, b2, out, N, 64, 256);

  log_softmax64<<<(N + 3) / 4, 256, 0, stream>>>(out, N);
}

// Round 4
// 452.015 us; speedup vs baseline: 1.4089x; 1.0493x over previous
//
#include <hip/hip_runtime.h>
#include <math.h>

#define EPS 1e-8f

__device__ __forceinline__ float wave_reduce_sum(float v) {
#pragma unroll
  for (int off = 32; off > 0; off >>= 1)
    v += __shfl_xor(v, off, 64);
  return v;
}

__device__ __forceinline__ float wave_reduce_max(float v) {
#pragma unroll
  for (int off = 32; off > 0; off >>= 1)
    v = fmaxf(v, __shfl_xor(v, off, 64));
  return v;
}

__device__ __forceinline__ float dot4(float4 a, float4 b) {
  return a.x * b.x + a.y * b.y + a.z * b.z + a.w * b.w;
}

// ---------------- counting sort by dst -> CSR ----------------
__global__ __launch_bounds__(256) void hist_kernel(const int* __restrict__ dst,
                                                   int* __restrict__ hist,
                                                   int E) {
  int e = blockIdx.x * blockDim.x + threadIdx.x;
  if (e < E) atomicAdd(&hist[dst[e]], 1);
}

__global__ __launch_bounds__(256) void scan_local(int* __restrict__ hist,
                                                  int* __restrict__ bsum,
                                                  int nb) {
  __shared__ int tsum[256];
  int t = threadIdx.x;
  int base = blockIdx.x * 1024 + t * 4;
  int v0 = 0, v1 = 0, v2 = 0, v3 = 0;
  if (base + 3 < nb) {
    int4 q = *(const int4*)&hist[base];
    v0 = q.x; v1 = q.y; v2 = q.z; v3 = q.w;
  } else {
    if (base + 0 < nb) v0 = hist[base + 0];
    if (base + 1 < nb) v1 = hist[base + 1];
    if (base + 2 < nb) v2 = hist[base + 2];
  }
  tsum[t] = v0 + v1 + v2 + v3;
  __syncthreads();
  for (int off = 1; off < 256; off <<= 1) {
    int u = 0;
    if (t >= off) u = tsum[t - off];
    __syncthreads();
    if (t >= off) tsum[t] += u;
    __syncthreads();
  }
  int excl = (t == 0) ? 0 : tsum[t - 1];
  int e0 = excl, e1 = excl + v0, e2 = e1 + v1, e3 = e2 + v2;
  if (base + 3 < nb) {
    *(int4*)&hist[base] = make_int4(e0, e1, e2, e3);
  } else {
    if (base + 0 < nb) hist[base + 0] = e0;
    if (base + 1 < nb) hist[base + 1] = e1;
    if (base + 2 < nb) hist[base + 2] = e2;
  }
  if (t == 255) bsum[blockIdx.x] = tsum[255];
}

__global__ __launch_bounds__(256) void scan_bsum(int* __restrict__ bsum,
                                                 int nblk) {
  __shared__ int sh[256];
  int t = threadIdx.x;
  sh[t] = (t < nblk) ? bsum[t] : 0;
  __syncthreads();
  for (int off = 1; off < 256; off <<= 1) {
    int u = 0;
    if (t >= off) u = sh[t - off];
    __syncthreads();
    if (t >= off) sh[t] += u;
    __syncthreads();
  }
  if (t < nblk) bsum[t] = (t == 0) ? 0 : sh[t - 1];
}

__global__ __launch_bounds__(256) void add_bsum(int* __restrict__ hist,
                                                const int* __restrict__ bsum,
                                                int nb) {
  int i = blockIdx.x * blockDim.x + threadIdx.x;
  if (i < nb) hist[i] += bsum[i >> 10];
}

__global__ __launch_bounds__(256) void scatter_kernel(
    const int* __restrict__ src, const int* __restrict__ dst,
    int* __restrict__ cursor, int* __restrict__ ssrc, int E) {
  int e = blockIdx.x * blockDim.x + threadIdx.x;
  if (e < E) {
    int pos = atomicAdd(&cursor[dst[e]], 1);
    ssrc[pos] = src[e];
  }
}

// ---------------- node norms ----------------
template <int D>
__global__ __launch_bounds__(256) void node_norm(const float* __restrict__ x,
                                                 float* __restrict__ norms,
                                                 int N) {
  constexpr int V = D / 64;
  int node = (int)((blockIdx.x * blockDim.x + threadIdx.x) >> 6);
  int lane = threadIdx.x & 63;
  if (node >= N) return;
  const float* row = x + (size_t)node * D + lane * V;
  float ss = 0.f;
  if constexpr (V == 2) {
    float2 t = *(const float2*)row;
    ss = t.x * t.x + t.y * t.y;
  } else {
    float4 t = *(const float4*)row;
    ss = t.x * t.x + t.y * t.y + t.z * t.z + t.w * t.w;
  }
  ss = wave_reduce_sum(ss);
  if (lane == 0) norms[node] = sqrtf(ss);
}

// ---------------- CSR conv, subgroup-16, software-pipelined ----------------
// One wave per dst node; 4 subgroups of 16 lanes, one edge per subgroup per
// iteration (4 edges in flight), 2-stage ping-pong prefetch (8 rows in
// flight). Each lane holds CH float4 slices: slice c = floats [c*64+l*4, +4).
template <int D>
__global__ __launch_bounds__(256) void csr_conv_sg(
    const float* __restrict__ feat, const float* __restrict__ norms,
    const int* __restrict__ ssrc, const int* __restrict__ endoff,
    float* __restrict__ agg, int N) {
  constexpr int CH = D / 64;  // float4 slices per lane per row
  int node = (int)((blockIdx.x * blockDim.x + threadIdx.x) >> 6);
  int lane = threadIdx.x & 63;
  if (node >= N) return;
  const int g = lane >> 4;   // subgroup 0..3
  const int l = lane & 15;   // lane within subgroup
  int start = (node == 0) ? 0 : endoff[node - 1];
  int end = endoff[node];

  // dst row (replicated across the 4 subgroups)
  const float* drow = feat + (size_t)node * D;
  float4 dv[CH];
#pragma unroll
  for (int c = 0; c < CH; ++c) dv[c] = *(const float4*)&drow[c * 64 + l * 4];
  float ssq = 0.f;
#pragma unroll
  for (int c = 0; c < CH; ++c) ssq += dot4(dv[c], dv[c]);
#pragma unroll
  for (int off = 1; off <= 8; off <<= 1) ssq += __shfl_xor(ssq, off);
  float nd = sqrtf(ssq);

  float4 acc[CH];
#pragma unroll
  for (int c = 0; c < CH; ++c) acc[c] = make_float4(0.f, 0.f, 0.f, 0.f);

  float4 svA[CH], svB[CH];
  float nsA = 0.f, nsB = 0.f;

  auto LOAD = [&](int e, float4 (&sv)[CH], float& ns) {
    bool pe = e < end;
    int s = pe ? ssrc[e] : 0;
    ns = pe ? norms[s] : 3.0e38f;
    const float* r = feat + (size_t)s * D;
#pragma unroll
    for (int c = 0; c < CH; ++c)
      sv[c] = pe ? *(const float4*)&r[c * 64 + l * 4]
                 : make_float4(0.f, 0.f, 0.f, 0.f);
  };
  auto PROC = [&](int e, float4 (&sv)[CH], float ns) {
    bool pe = e < end;
    float d = 0.f;
#pragma unroll
    for (int c = 0; c < CH; ++c) d += dot4(sv[c], dv[c]);
#pragma unroll
    for (int off = 1; off <= 8; off <<= 1) d += __shfl_xor(d, off);
    if (pe && d > 0.5f * fmaxf(ns * nd, EPS)) {
#pragma unroll
      for (int c = 0; c < CH; ++c) {
        acc[c].x += sv[c].x; acc[c].y += sv[c].y;
        acc[c].z += sv[c].z; acc[c].w += sv[c].w;
      }
    }
  };

  int eA = start + g;      // this subgroup's edge in even iterations
  int eB = eA + 4;         // and in odd iterations
  LOAD(eA, svA, nsA);
  for (int eb = start; eb < end; eb += 8) {
    LOAD(eB, svB, nsB);    // prefetch odd slot
    PROC(eA, svA, nsA);
    eA += 8;
    LOAD(eA, svA, nsA);    // prefetch next even slot
    PROC(eB, svB, nsB);
    eB += 8;
  }

  // fold the 4 subgroup accumulators: sum lanes {l, l+16, l+32, l+48}
#pragma unroll
  for (int c = 0; c < CH; ++c) {
    acc[c].x += __shfl_xor(acc[c].x, 16); acc[c].x += __shfl_xor(acc[c].x, 32);
    acc[c].y += __shfl_xor(acc[c].y, 16); acc[c].y += __shfl_xor(acc[c].y, 32);
    acc[c].z += __shfl_xor(acc[c].z, 16); acc[c].z += __shfl_xor(acc[c].z, 32);
    acc[c].w += __shfl_xor(acc[c].w, 16); acc[c].w += __shfl_xor(acc[c].w, 32);
  }
  // self-loop (exact reference formula)
  bool selfpass = ssq > 0.5f * fmaxf(ssq, EPS);
  if (g == 0) {
    float* arow = agg + (size_t)node * D;
#pragma unroll
    for (int c = 0; c < CH; ++c) {
      float4 o = acc[c];
      if (selfpass) { o.x += dv[c].x; o.y += dv[c].y; o.z += dv[c].z; o.w += dv[c].w; }
      *(float4*)&arow[c * 64 + l * 4] = o;
    }
  }
}

// ---------------- GEMM: C = act(A @ W^T + b), 64x64 tile ----------------
template <int BK, bool RELU>
__global__ __launch_bounds__(256) void gemm_bias(
    const float* __restrict__ A, const float* __restrict__ W,
    const float* __restrict__ bias, float* __restrict__ C,
    int M, int N, int K) {
  __shared__ float As[BK][68];
  __shared__ float Bs[BK][68];
  const int tid = threadIdx.x;
  const int m0 = blockIdx.x * 64;
  const int n0 = blockIdx.y * 64;
  const int mv = tid >> 3;
  const int kv = (tid & 7) * 4;
  float acc[4][4] = {};
  for (int k0 = 0; k0 < K; k0 += BK) {
#pragma unroll
    for (int i = 0; i < 2; ++i) {
      int r = mv + i * 32;
      int gm = m0 + r;
      float4 a = (gm < M) ? *(const float4*)&A[(size_t)gm * K + k0 + kv]
                          : make_float4(0.f, 0.f, 0.f, 0.f);
      As[kv + 0][r] = a.x; As[kv + 1][r] = a.y;
      As[kv + 2][r] = a.z; As[kv + 3][r] = a.w;
      float4 b = *(const float4*)&W[(size_t)(n0 + r) * K + k0 + kv];
      Bs[kv + 0][r] = b.x; Bs[kv + 1][r] = b.y;
      Bs[kv + 2][r] = b.z; Bs[kv + 3][r] = b.w;
    }
    __syncthreads();
    const int ms = (tid & 15) * 4;
    const int ns = (tid >> 4) * 4;
#pragma unroll
    for (int kk = 0; kk < BK; ++kk) {
      float4 a4 = *(const float4*)&As[kk][ms];
      float4 b4 = *(const float4*)&Bs[kk][ns];
      float av[4] = {a4.x, a4.y, a4.z, a4.w};
      float bv[4] = {b4.x, b4.y, b4.z, b4.w};
#pragma unroll
      for (int i = 0; i < 4; ++i)
#pragma unroll
        for (int j = 0; j < 4; ++j) acc[i][j] += av[i] * bv[j];
    }
    __syncthreads();
  }
  const int ms = (tid & 15) * 4;
  const int ns = (tid >> 4) * 4;
  float4 bb = *(const float4*)&bias[n0 + ns];
  float bv[4] = {bb.x, bb.y, bb.z, bb.w};
#pragma unroll
  for (int i = 0; i < 4; ++i) {
    int gm = m0 + ms + i;
    if (gm < M) {
      float t0 = acc[i][0] + bv[0];
      float t1 = acc[i][1] + bv[1];
      float t2 = acc[i][2] + bv[2];
      float t3 = acc[i][3] + bv[3];
      if (RELU) {
        t0 = fmaxf(t0, 0.f); t1 = fmaxf(t1, 0.f);
        t2 = fmaxf(t2, 0.f); t3 = fmaxf(t3, 0.f);
      }
      float4 o = {t0, t1, t2, t3};
      *(float4*)&C[(size_t)gm * N + n0 + ns] = o;
    }
  }
}

__global__ __launch_bounds__(256) void log_softmax64(float* __restrict__ out,
                                                     int N) {
  int row = (int)((blockIdx.x * blockDim.x + threadIdx.x) >> 6);
  int lane = threadIdx.x & 63;
  if (row >= N) return;
  float v = out[(size_t)row * 64 + lane];
  float mx = wave_reduce_max(v);
  float e = expf(v - mx);
  float s = wave_reduce_sum(e);
  out[(size_t)row * 64 + lane] = v - mx - logf(s);
}

extern "C" void kernel_launch(void* const* d_in, const int* in_sizes, int n_in,
                              void* d_out, int out_size, void* d_ws,
                              size_t ws_size, hipStream_t stream) {
  const float* x  = (const float*)d_in[0];
  const int* eidx = (const int*)d_in[1];
  const float* W1 = (const float*)d_in[2];
  const float* b1 = (const float*)d_in[3];
  const float* W2 = (const float*)d_in[4];
  const float* b2 = (const float*)d_in[5];
  float* out = (float*)d_out;

  const int N = in_sizes[0] / 128;  // 50000
  const int E = in_sizes[1] / 2;    // 800000
  const int* src = eidx;
  const int* dst = eidx + E;

  float* h     = (float*)d_ws;
  float* agg   = h + (size_t)N * 256;
  float* norms = agg + (size_t)N * 256;
  float* normh = norms + N;
  int* cursor  = (int*)(normh + N);
  int* ssrc    = cursor + N;
  int* bsum    = ssrc + E;

  const int nblk = (N + 1023) / 1024;

  // ---- build CSR (by dst), shared by both layers ----
  hipMemsetAsync(cursor, 0, (size_t)N * sizeof(int), stream);
  hist_kernel<<<(E + 255) / 256, 256, 0, stream>>>(dst, cursor, E);
  scan_local<<<nblk, 256, 0, stream>>>(cursor, bsum, N);
  scan_bsum<<<1, 256, 0, stream>>>(bsum, nblk);
  add_bsum<<<(N + 255) / 256, 256, 0, stream>>>(cursor, bsum, N);
  scatter_kernel<<<(E + 255) / 256, 256, 0, stream>>>(src, dst, cursor, ssrc, E);
  // cursor[d] == end offset of node d

  // ---- layer 1 (D=128) ----
  node_norm<128><<<(N + 3) / 4, 256, 0, stream>>>(x, norms, N);
  csr_conv_sg<128><<<(N + 3) / 4, 256, 0, stream>>>(x, norms, ssrc, cursor,
                                                    agg, N);
  gemm_bias<32, true><<<dim3((N + 63) / 64, 4), 256, 0, stream>>>(
      agg, W1, b1, h, N, 256, 128);

  // ---- layer 2 (D=256) ----
  node_norm<256><<<(N + 3) / 4, 256, 0, stream>>>(h, normh, N);
  csr_conv_sg<256><<<(N + 3) / 4, 256, 0, stream>>>(h, normh, ssrc, cursor,
                                                    agg, N);
  gemm_bias<32, false><<<dim3((N + 63) / 64, 1), 256, 0, stream>>>(
      agg, W2, b2, out, N, 64, 256);

  log_softmax64<<<(N + 3) / 4, 256, 0, stream>>>(out, N);
}

// Round 5
// 416.384 us; speedup vs baseline: 1.5295x; 1.0856x over previous
//
#include <hip/hip_runtime.h>
#include <math.h>

#define EPS 1e-8f

__device__ __forceinline__ float wave_reduce_sum(float v) {
#pragma unroll
  for (int off = 32; off > 0; off >>= 1)
    v += __shfl_xor(v, off, 64);
  return v;
}

__device__ __forceinline__ float wave_reduce_max(float v) {
#pragma unroll
  for (int off = 32; off > 0; off >>= 1)
    v = fmaxf(v, __shfl_xor(v, off, 64));
  return v;
}

__device__ __forceinline__ float sg16_reduce(float v) {
#pragma unroll
  for (int off = 1; off <= 8; off <<= 1) v += __shfl_xor(v, off);
  return v;
}

__device__ __forceinline__ float dot4(float4 a, float4 b) {
  return a.x * b.x + a.y * b.y + a.z * b.z + a.w * b.w;
}

// truncated-bf16 unpack: two fp32 from one uint holding two ushorts
__device__ __forceinline__ void unpack2(unsigned int w, float& a, float& b) {
  a = __uint_as_float(w << 16);
  b = __uint_as_float(w & 0xffff0000u);
}
__device__ __forceinline__ float4 unpack4_lo(uint4 w) {  // elems 0..3
  float4 r; unpack2(w.x, r.x, r.y); unpack2(w.y, r.z, r.w); return r;
}
__device__ __forceinline__ float4 unpack4_hi(uint4 w) {  // elems 4..7
  float4 r; unpack2(w.z, r.x, r.y); unpack2(w.w, r.z, r.w); return r;
}
// bit-exact reconstruct: fp32 = (hi<<16) | lo
__device__ __forceinline__ void recon2(unsigned int whi, unsigned int wlo,
                                       float& a, float& b) {
  a = __uint_as_float((whi << 16) | (wlo & 0xffffu));
  b = __uint_as_float((whi & 0xffff0000u) | (wlo >> 16));
}

// ---------------- counting sort by dst -> CSR ----------------
__global__ __launch_bounds__(256) void hist_kernel(const int* __restrict__ dst,
                                                   int* __restrict__ hist,
                                                   int E) {
  int e = blockIdx.x * blockDim.x + threadIdx.x;
  if (e < E) atomicAdd(&hist[dst[e]], 1);
}

__global__ __launch_bounds__(256) void scan_local(int* __restrict__ hist,
                                                  int* __restrict__ bsum,
                                                  int nb) {
  __shared__ int tsum[256];
  int t = threadIdx.x;
  int base = blockIdx.x * 1024 + t * 4;
  int v0 = 0, v1 = 0, v2 = 0, v3 = 0;
  if (base + 3 < nb) {
    int4 q = *(const int4*)&hist[base];
    v0 = q.x; v1 = q.y; v2 = q.z; v3 = q.w;
  } else {
    if (base + 0 < nb) v0 = hist[base + 0];
    if (base + 1 < nb) v1 = hist[base + 1];
    if (base + 2 < nb) v2 = hist[base + 2];
  }
  tsum[t] = v0 + v1 + v2 + v3;
  __syncthreads();
  for (int off = 1; off < 256; off <<= 1) {
    int u = 0;
    if (t >= off) u = tsum[t - off];
    __syncthreads();
    if (t >= off) tsum[t] += u;
    __syncthreads();
  }
  int excl = (t == 0) ? 0 : tsum[t - 1];
  int e0 = excl, e1 = excl + v0, e2 = e1 + v1, e3 = e2 + v2;
  if (base + 3 < nb) {
    *(int4*)&hist[base] = make_int4(e0, e1, e2, e3);
  } else {
    if (base + 0 < nb) hist[base + 0] = e0;
    if (base + 1 < nb) hist[base + 1] = e1;
    if (base + 2 < nb) hist[base + 2] = e2;
  }
  if (t == 255) bsum[blockIdx.x] = tsum[255];
}

__global__ __launch_bounds__(256) void scan_bsum(int* __restrict__ bsum,
                                                 int nblk) {
  __shared__ int sh[256];
  int t = threadIdx.x;
  sh[t] = (t < nblk) ? bsum[t] : 0;
  __syncthreads();
  for (int off = 1; off < 256; off <<= 1) {
    int u = 0;
    if (t >= off) u = sh[t - off];
    __syncthreads();
    if (t >= off) sh[t] += u;
    __syncthreads();
  }
  if (t < nblk) bsum[t] = (t == 0) ? 0 : sh[t - 1];
}

__global__ __launch_bounds__(256) void add_bsum(int* __restrict__ hist,
                                                const int* __restrict__ bsum,
                                                int nb) {
  int i = blockIdx.x * blockDim.x + threadIdx.x;
  if (i < nb) hist[i] += bsum[i >> 10];
}

__global__ __launch_bounds__(256) void scatter_kernel(
    const int* __restrict__ src, const int* __restrict__ dst,
    int* __restrict__ cursor, int* __restrict__ ssrc, int E) {
  int e = blockIdx.x * blockDim.x + threadIdx.x;
  if (e < E) {
    int pos = atomicAdd(&cursor[dst[e]], 1);
    ssrc[pos] = src[e];
  }
}

// ---------------- truncate fp32 -> hi16 plane (8 floats/thread) -----------
__global__ __launch_bounds__(256) void trunc16(const float* __restrict__ in,
                                               unsigned short* __restrict__ op,
                                               int n8) {
  int i = blockIdx.x * blockDim.x + threadIdx.x;
  if (i >= n8) return;
  const float4* p = (const float4*)(in + (size_t)i * 8);
  float4 a = p[0], b = p[1];
  uint4 w;
  w.x = (__float_as_uint(a.x) >> 16) | (__float_as_uint(a.y) & 0xffff0000u);
  w.y = (__float_as_uint(a.z) >> 16) | (__float_as_uint(a.w) & 0xffff0000u);
  w.z = (__float_as_uint(b.x) >> 16) | (__float_as_uint(b.y) & 0xffff0000u);
  w.w = (__float_as_uint(b.z) >> 16) | (__float_as_uint(b.w) & 0xffff0000u);
  *(uint4*)(op + (size_t)i * 8) = w;
}

// ---------------- node norms ----------------
template <int D>
__global__ __launch_bounds__(256) void node_norm(const float* __restrict__ x,
                                                 float* __restrict__ norms,
                                                 int N) {
  constexpr int V = D / 64;
  int node = (int)((blockIdx.x * blockDim.x + threadIdx.x) >> 6);
  int lane = threadIdx.x & 63;
  if (node >= N) return;
  const float* row = x + (size_t)node * D + lane * V;
  float ss = 0.f;
  if constexpr (V == 2) {
    float2 t = *(const float2*)row;
    ss = t.x * t.x + t.y * t.y;
  } else {
    float4 t = *(const float4*)row;
    ss = t.x * t.x + t.y * t.y + t.z * t.z + t.w * t.w;
  }
  ss = wave_reduce_sum(ss);
  if (lane == 0) norms[node] = sqrtf(ss);
}

// norms of the (hi|lo)-reconstructed D=256 table
__global__ __launch_bounds__(256) void node_norm_planes(
    const unsigned short* __restrict__ hi, const unsigned short* __restrict__ lo,
    float* __restrict__ norms, int N) {
  int node = (int)((blockIdx.x * blockDim.x + threadIdx.x) >> 6);
  int lane = threadIdx.x & 63;
  if (node >= N) return;
  size_t idx = (size_t)node * 256 + lane * 4;
  uint2 whi = *(const uint2*)(hi + idx);
  uint2 wlo = *(const uint2*)(lo + idx);
  float a, b, c, d;
  recon2(whi.x, wlo.x, a, b);
  recon2(whi.y, wlo.y, c, d);
  float ss = a * a + b * b + c * c + d * d;
  ss = wave_reduce_sum(ss);
  if (lane == 0) norms[node] = sqrtf(ss);
}

// ---------------- CSR conv with hi16 screen + exact recheck ----------------
// One wave per dst node; 4 subgroups x 16 lanes, ping-pong prefetch of hi16
// screen rows. Screen error bound: |ddot| <= 2^-7 * ||s||*||d|| -> margin
// 0.011*denom guarantees screen-fails are true fails. Edges above thr-m take
// the exact fp32 path (identical gate to the all-fp32 kernel).
template <int D, bool SPLIT>
__global__ __launch_bounds__(256) void csr_conv_scr(
    const float* __restrict__ xf,            // fp32 table (!SPLIT)
    const unsigned short* __restrict__ hi,   // hi16 screen table
    const unsigned short* __restrict__ lo,   // lo16 plane (SPLIT)
    const float* __restrict__ norms,
    const int* __restrict__ ssrc, const int* __restrict__ endoff,
    float* __restrict__ agg, int N) {
  constexpr int CH = D / 64;   // float4 slices per lane (2 or 4)
  constexpr int U = D / 128;   // uint4 screen loads per lane (1 or 2)
  int node = (int)((blockIdx.x * blockDim.x + threadIdx.x) >> 6);
  int lane = threadIdx.x & 63;
  if (node >= N) return;
  const int g = lane >> 4;
  const int l = lane & 15;
  int start = (node == 0) ? 0 : endoff[node - 1];
  int end = endoff[node];

  // exact dst row, lane l covers elems [u*128 + l*8, +8)
  float4 dv[CH];
  if constexpr (SPLIT) {
#pragma unroll
    for (int u = 0; u < U; ++u) {
      size_t idx = (size_t)node * D + u * 128 + l * 8;
      uint4 whi = *(const uint4*)(hi + idx);
      uint4 wlo = *(const uint4*)(lo + idx);
      recon2(whi.x, wlo.x, dv[2 * u].x, dv[2 * u].y);
      recon2(whi.y, wlo.y, dv[2 * u].z, dv[2 * u].w);
      recon2(whi.z, wlo.z, dv[2 * u + 1].x, dv[2 * u + 1].y);
      recon2(whi.w, wlo.w, dv[2 * u + 1].z, dv[2 * u + 1].w);
    }
  } else {
#pragma unroll
    for (int u = 0; u < U; ++u) {
      const float* drow = xf + (size_t)node * D + u * 128 + l * 8;
      dv[2 * u] = *(const float4*)drow;
      dv[2 * u + 1] = *(const float4*)(drow + 4);
    }
  }
  float ssq = 0.f;
#pragma unroll
  for (int c = 0; c < CH; ++c) ssq += dot4(dv[c], dv[c]);
  ssq = sg16_reduce(ssq);
  float nd = sqrtf(ssq);

  float4 acc[CH];
#pragma unroll
  for (int c = 0; c < CH; ++c) acc[c] = make_float4(0.f, 0.f, 0.f, 0.f);

  uint4 wA[U], wB[U];
  float nsA = 1.f, nsB = 1.f;

  auto LOAD = [&](int e, uint4 (&w)[U], float& ns) {
    bool pe = e < end;
    int s = pe ? ssrc[e] : 0;
    ns = pe ? norms[s] : 1.0f;
#pragma unroll
    for (int u = 0; u < U; ++u)
      w[u] = pe ? *(const uint4*)(hi + (size_t)s * D + u * 128 + l * 8)
                : make_uint4(0, 0, 0, 0);
  };
  auto PROC = [&](int e, uint4 (&w)[U], float ns) {
    bool pe = e < end;
    float d = 0.f;
#pragma unroll
    for (int u = 0; u < U; ++u) {
      d += dot4(unpack4_lo(w[u]), dv[2 * u]);
      d += dot4(unpack4_hi(w[u]), dv[2 * u + 1]);
    }
    d = sg16_reduce(d);
    float denom = fmaxf(ns * nd, EPS);
    float thr = 0.5f * denom;
    float m = 0.011f * denom + 1e-7f;
    if (pe && d > thr - m) {
      // exact fp32 path (rare): gather full-precision row, same gate as ever
      int s = ssrc[e];
      float4 sv[CH];
      if constexpr (SPLIT) {
#pragma unroll
        for (int u = 0; u < U; ++u) {
          size_t idx = (size_t)s * D + u * 128 + l * 8;
          uint4 whi = *(const uint4*)(hi + idx);
          uint4 wlo = *(const uint4*)(lo + idx);
          recon2(whi.x, wlo.x, sv[2 * u].x, sv[2 * u].y);
          recon2(whi.y, wlo.y, sv[2 * u].z, sv[2 * u].w);
          recon2(whi.z, wlo.z, sv[2 * u + 1].x, sv[2 * u + 1].y);
          recon2(whi.w, wlo.w, sv[2 * u + 1].z, sv[2 * u + 1].w);
        }
      } else {
#pragma unroll
        for (int u = 0; u < U; ++u) {
          const float* r = xf + (size_t)s * D + u * 128 + l * 8;
          sv[2 * u] = *(const float4*)r;
          sv[2 * u + 1] = *(const float4*)(r + 4);
        }
      }
      float dx = 0.f;
#pragma unroll
      for (int c = 0; c < CH; ++c) dx += dot4(sv[c], dv[c]);
      dx = sg16_reduce(dx);
      if (dx > thr) {
#pragma unroll
        for (int c = 0; c < CH; ++c) {
          acc[c].x += sv[c].x; acc[c].y += sv[c].y;
          acc[c].z += sv[c].z; acc[c].w += sv[c].w;
        }
      }
    }
  };

  int eA = start + g;
  int eB = eA + 4;
  LOAD(eA, wA, nsA);
  for (int eb = start; eb < end; eb += 8) {
    LOAD(eB, wB, nsB);
    PROC(eA, wA, nsA);
    eA += 8;
    LOAD(eA, wA, nsA);
    PROC(eB, wB, nsB);
    eB += 8;
  }

#pragma unroll
  for (int c = 0; c < CH; ++c) {
    acc[c].x += __shfl_xor(acc[c].x, 16); acc[c].x += __shfl_xor(acc[c].x, 32);
    acc[c].y += __shfl_xor(acc[c].y, 16); acc[c].y += __shfl_xor(acc[c].y, 32);
    acc[c].z += __shfl_xor(acc[c].z, 16); acc[c].z += __shfl_xor(acc[c].z, 32);
    acc[c].w += __shfl_xor(acc[c].w, 16); acc[c].w += __shfl_xor(acc[c].w, 32);
  }
  bool selfpass = ssq > 0.5f * fmaxf(ssq, EPS);
  if (g == 0) {
#pragma unroll
    for (int u = 0; u < U; ++u) {
      float* arow = agg + (size_t)node * D + u * 128 + l * 8;
      float4 o0 = acc[2 * u], o1 = acc[2 * u + 1];
      if (selfpass) {
        o0.x += dv[2 * u].x; o0.y += dv[2 * u].y;
        o0.z += dv[2 * u].z; o0.w += dv[2 * u].w;
        o1.x += dv[2 * u + 1].x; o1.y += dv[2 * u + 1].y;
        o1.z += dv[2 * u + 1].z; o1.w += dv[2 * u + 1].w;
      }
      *(float4*)arow = o0;
      *(float4*)(arow + 4) = o1;
    }
  }
}

// ---------------- GEMM: C = act(A @ W^T + b), 64x64 tile ----------------
// TOSPLIT: write result as hi16/lo16 bit-planes instead of fp32.
template <int BK, bool RELU, bool TOSPLIT>
__global__ __launch_bounds__(256) void gemm_bias(
    const float* __restrict__ A, const float* __restrict__ W,
    const float* __restrict__ bias, float* __restrict__ C,
    unsigned short* __restrict__ hiP, unsigned short* __restrict__ loP,
    int M, int N, int K) {
  __shared__ float As[BK][68];
  __shared__ float Bs[BK][68];
  const int tid = threadIdx.x;
  const int m0 = blockIdx.x * 64;
  const int n0 = blockIdx.y * 64;
  const int mv = tid >> 3;
  const int kv = (tid & 7) * 4;
  float acc[4][4] = {};
  for (int k0 = 0; k0 < K; k0 += BK) {
#pragma unroll
    for (int i = 0; i < 2; ++i) {
      int r = mv + i * 32;
      int gm = m0 + r;
      float4 a = (gm < M) ? *(const float4*)&A[(size_t)gm * K + k0 + kv]
                          : make_float4(0.f, 0.f, 0.f, 0.f);
      As[kv + 0][r] = a.x; As[kv + 1][r] = a.y;
      As[kv + 2][r] = a.z; As[kv + 3][r] = a.w;
      float4 b = *(const float4*)&W[(size_t)(n0 + r) * K + k0 + kv];
      Bs[kv + 0][r] = b.x; Bs[kv + 1][r] = b.y;
      Bs[kv + 2][r] = b.z; Bs[kv + 3][r] = b.w;
    }
    __syncthreads();
    const int ms = (tid & 15) * 4;
    const int ns = (tid >> 4) * 4;
#pragma unroll
    for (int kk = 0; kk < BK; ++kk) {
      float4 a4 = *(const float4*)&As[kk][ms];
      float4 b4 = *(const float4*)&Bs[kk][ns];
      float av[4] = {a4.x, a4.y, a4.z, a4.w};
      float bv[4] = {b4.x, b4.y, b4.z, b4.w};
#pragma unroll
      for (int i = 0; i < 4; ++i)
#pragma unroll
        for (int j = 0; j < 4; ++j) acc[i][j] += av[i] * bv[j];
    }
    __syncthreads();
  }
  const int ms = (tid & 15) * 4;
  const int ns = (tid >> 4) * 4;
  float4 bb = *(const float4*)&bias[n0 + ns];
  float bv[4] = {bb.x, bb.y, bb.z, bb.w};
#pragma unroll
  for (int i = 0; i < 4; ++i) {
    int gm = m0 + ms + i;
    if (gm < M) {
      float t0 = acc[i][0] + bv[0];
      float t1 = acc[i][1] + bv[1];
      float t2 = acc[i][2] + bv[2];
      float t3 = acc[i][3] + bv[3];
      if (RELU) {
        t0 = fmaxf(t0, 0.f); t1 = fmaxf(t1, 0.f);
        t2 = fmaxf(t2, 0.f); t3 = fmaxf(t3, 0.f);
      }
      size_t idx = (size_t)gm * N + n0 + ns;
      if (TOSPLIT) {
        unsigned int b0 = __float_as_uint(t0), b1 = __float_as_uint(t1);
        unsigned int b2 = __float_as_uint(t2), b3 = __float_as_uint(t3);
        uint2 whi = {(b0 >> 16) | (b1 & 0xffff0000u),
                     (b2 >> 16) | (b3 & 0xffff0000u)};
        uint2 wlo = {(b0 & 0xffffu) | (b1 << 16),
                     (b2 & 0xffffu) | (b3 << 16)};
        *(uint2*)(hiP + idx) = whi;
        *(uint2*)(loP + idx) = wlo;
      } else {
        float4 o = {t0, t1, t2, t3};
        *(float4*)&C[idx] = o;
      }
    }
  }
}

__global__ __launch_bounds__(256) void log_softmax64(float* __restrict__ out,
                                                     int N) {
  int row = (int)((blockIdx.x * blockDim.x + threadIdx.x) >> 6);
  int lane = threadIdx.x & 63;
  if (row >= N) return;
  float v = out[(size_t)row * 64 + lane];
  float mx = wave_reduce_max(v);
  float e = expf(v - mx);
  float s = wave_reduce_sum(e);
  out[(size_t)row * 64 + lane] = v - mx - logf(s);
}

extern "C" void kernel_launch(void* const* d_in, const int* in_sizes, int n_in,
                              void* d_out, int out_size, void* d_ws,
                              size_t ws_size, hipStream_t stream) {
  const float* x  = (const float*)d_in[0];
  const int* eidx = (const int*)d_in[1];
  const float* W1 = (const float*)d_in[2];
  const float* b1 = (const float*)d_in[3];
  const float* W2 = (const float*)d_in[4];
  const float* b2 = (const float*)d_in[5];
  float* out = (float*)d_out;

  const int N = in_sizes[0] / 128;  // 50000
  const int E = in_sizes[1] / 2;    // 800000
  const int* src = eidx;
  const int* dst = eidx + E;

  // ws (floats): agg[N*256] | norms[N] | normh[N] | cursor[N](int) |
  //   ssrc[E](int) | bsum[256](int) | hi[N*256 u16] | lo[N*256 u16]
  // xbf (N*128 u16) overlaps hi region (dead before GEMM1 writes hi).
  float* agg   = (float*)d_ws;
  float* norms = agg + (size_t)N * 256;
  float* normh = norms + N;
  int* cursor  = (int*)(normh + N);
  int* ssrc    = cursor + N;
  int* bsum    = ssrc + E;
  unsigned short* hiP = (unsigned short*)(bsum + 256);
  unsigned short* loP = hiP + (size_t)N * 256;
  unsigned short* xbf = hiP;  // overlap

  const int nblk = (N + 1023) / 1024;

  // ---- build CSR (by dst), shared by both layers ----
  hipMemsetAsync(cursor, 0, (size_t)N * sizeof(int), stream);
  hist_kernel<<<(E + 255) / 256, 256, 0, stream>>>(dst, cursor, E);
  scan_local<<<nblk, 256, 0, stream>>>(cursor, bsum, N);
  scan_bsum<<<1, 256, 0, stream>>>(bsum, nblk);
  add_bsum<<<(N + 255) / 256, 256, 0, stream>>>(cursor, bsum, N);
  scatter_kernel<<<(E + 255) / 256, 256, 0, stream>>>(src, dst, cursor, ssrc, E);

  // ---- layer 1 (D=128): screen table = truncated x ----
  trunc16<<<((N * 128 / 8) + 255) / 256, 256, 0, stream>>>(x, xbf, N * 128 / 8);
  node_norm<128><<<(N + 3) / 4, 256, 0, stream>>>(x, norms, N);
  csr_conv_scr<128, false><<<(N + 3) / 4, 256, 0, stream>>>(
      x, xbf, nullptr, norms, ssrc, cursor, agg, N);
  gemm_bias<32, true, true><<<dim3((N + 63) / 64, 4), 256, 0, stream>>>(
      agg, W1, b1, nullptr, hiP, loP, N, 256, 128);

  // ---- layer 2 (D=256): h lives only as hi/lo planes ----
  node_norm_planes<<<(N + 3) / 4, 256, 0, stream>>>(hiP, loP, normh, N);
  csr_conv_scr<256, true><<<(N + 3) / 4, 256, 0, stream>>>(
      nullptr, hiP, loP, normh, ssrc, cursor, agg, N);
  gemm_bias<32, false, false><<<dim3((N + 63) / 64, 1), 256, 0, stream>>>(
      agg, W2, b2, out, nullptr, nullptr, N, 64, 256);

  log_softmax64<<<(N + 3) / 4, 256, 0, stream>>>(out, N);
}